// Round 2
// baseline (3352.439 us; speedup 1.0000x reference)
//
#include <hip/hip_runtime.h>
#include <hip/hip_bf16.h>
#include <stdint.h>

// Problem constants
#define B_SZ   64
#define L_SEQ  512
#define DIN    1024
#define HDIM   1024
#define G4     4096   // 4*H
// out layout: outputs [64*512*1024], h_fin [64*1024], c_fin [64*1024]
#define OUT_HFIN 33554432L
#define OUT_CFIN 33619968L

typedef float  f32x4 __attribute__((ext_vector_type(4)));
typedef short  s16x8 __attribute__((ext_vector_type(8)));
typedef unsigned short u16;
typedef unsigned char  u8;
typedef unsigned long long u64;

// ---- workspace layout (bytes) ----
#define OFF_XBF   0ULL
#define OFF_WX    67108864ULL
#define OFF_WH    75497472ULL
#define OFF_XPROJ 83886080ULL
#define OFF_HBUF  352321536ULL   // 2 * 128KB mailbox (ping-pong), same 256KB as before
#define OFF_FLG   352583680ULL   // 4 groups * 256 u8 wave-flags = 1KB (same size as before)

static __device__ __forceinline__ u16 f2bf(float f) {
    __hip_bfloat16 h = __float2bfloat16(f);
    return *reinterpret_cast<u16*>(&h);
}
static __device__ __forceinline__ float bf2f(u16 u) {
    union { uint32_t i; float f; } v;
    v.i = ((uint32_t)u) << 16;
    return v.f;
}
static __device__ __forceinline__ float fsigmoid(float x) {
    return __builtin_amdgcn_rcpf(1.0f + __expf(-x));
}
static __device__ __forceinline__ float ftanh(float x) {
    return 1.0f - 2.0f * __builtin_amdgcn_rcpf(1.0f + __expf(2.0f * x));
}
// async global->LDS, 16B per lane. LDS ptr must be wave-uniform (HW writes
// base + lane*16); global ptr is per-lane.
static __device__ __forceinline__ void gload_lds16(const u16* g, u16* l) {
    __builtin_amdgcn_global_load_lds((const __attribute__((address_space(1))) void*)g,
                                     (__attribute__((address_space(3))) void*)l, 16, 0, 0);
}

// ============================ prep: fp32 -> bf16 ============================
__global__ void prep_kernel(const float* __restrict__ x, const float* __restrict__ W,
                            u16* __restrict__ xbf, u16* __restrict__ wx,
                            u16* __restrict__ wh, int* __restrict__ flg) {
    long tid = (long)blockIdx.x * blockDim.x + threadIdx.x;
    long stride = (long)gridDim.x * blockDim.x;
    const long NX4 = 33554432 / 4;
    for (long i = tid; i < NX4; i += stride) {
        float4 v = ((const float4*)x)[i];
        ushort4 o;
        o.x = f2bf(v.x); o.y = f2bf(v.y); o.z = f2bf(v.z); o.w = f2bf(v.w);
        ((ushort4*)xbf)[i] = o;
    }
    const long NW4 = 8388608 / 4;
    for (long i = tid; i < NW4; i += stride) {
        float4 v = ((const float4*)W)[i];
        long f = i * 4;
        long n = f >> 11;        // row of W (2048 wide)
        long c = f & 2047;
        ushort4 o;
        o.x = f2bf(v.x); o.y = f2bf(v.y); o.z = f2bf(v.z); o.w = f2bf(v.w);
        u16* dst = (c < 1024) ? &wh[n * 1024 + c] : &wx[n * 1024 + (c - 1024)];
        *(ushort4*)dst = o;
    }
    // zero 1KB of wave-flags (4 groups * 64 jc * 4 waves, u8 each)
    if (blockIdx.x == 0 && threadIdx.x < 256) flg[threadIdx.x] = 0;
}

// ==================== phase 1: x_proj = x @ Wx^T + b (bf16 out) =============
// m97-structure: global_load_lds dwordx4 staging + double-buffered LDS,
// one barrier per K-step. (unchanged from round 1)
__global__ __launch_bounds__(256) void xproj_gemm(const u16* __restrict__ xbf,
                                                  const u16* __restrict__ wxbf,
                                                  const float* __restrict__ bias,
                                                  u16* __restrict__ xproj) {
    __shared__ u16 As[2][128 * 32];
    __shared__ u16 Bs[2][128 * 32];
    const int tid  = threadIdx.x;
    const int lane = tid & 63;
    const int w    = tid >> 6;
    const int wm   = w >> 1, wn = w & 1;
    const int l15  = lane & 15, quad = lane >> 4;
    const int m0 = blockIdx.y * 128;
    const int n0 = blockIdx.x * 128;

    const u16* ga = xbf  + (long)(m0 + (tid >> 2)) * 1024 + (tid & 3) * 8;
    const u16* gb = wxbf + (long)(n0 + (tid >> 2)) * 1024 + (tid & 3) * 8;

    f32x4 acc[4][4];
#pragma unroll
    for (int i = 0; i < 4; ++i)
#pragma unroll
        for (int j = 0; j < 4; ++j) acc[i][j] = 0.0f;

#define STAGE(buf, k0)                                                    \
    do {                                                                  \
        gload_lds16(ga + (k0),         &As[buf][w * 512]);                \
        gload_lds16(ga + 65536 + (k0), &As[buf][2048 + w * 512]);         \
        gload_lds16(gb + (k0),         &Bs[buf][w * 512]);                \
        gload_lds16(gb + 65536 + (k0), &Bs[buf][2048 + w * 512]);         \
    } while (0)

    STAGE(0, 0);
    __syncthreads();

    for (int kt = 0; kt < 32; ++kt) {
        const int cur = kt & 1;
        if (kt < 31) STAGE(cur ^ 1, (kt + 1) * 32);

        s16x8 af[4], bfr[4];
#pragma unroll
        for (int mt = 0; mt < 4; ++mt)
            af[mt] = *(const s16x8*)&As[cur][(wm * 64 + mt * 16 + l15) * 32 + quad * 8];
#pragma unroll
        for (int nt = 0; nt < 4; ++nt)
            bfr[nt] = *(const s16x8*)&Bs[cur][(wn * 64 + nt * 16 + l15) * 32 + quad * 8];
#pragma unroll
        for (int mt = 0; mt < 4; ++mt)
#pragma unroll
            for (int nt = 0; nt < 4; ++nt)
                acc[mt][nt] = __builtin_amdgcn_mfma_f32_16x16x32_bf16(af[mt], bfr[nt], acc[mt][nt], 0, 0, 0);

        __syncthreads();
    }
#undef STAGE

#pragma unroll
    for (int nt = 0; nt < 4; ++nt) {
        int n = n0 + wn * 64 + nt * 16 + l15;
        float bv = bias[n];
#pragma unroll
        for (int mt = 0; mt < 4; ++mt) {
            int mbase = m0 + wm * 64 + mt * 16 + quad * 4;
#pragma unroll
            for (int r = 0; r < 4; ++r)
                xproj[(long)(mbase + r) * 4096 + n] = f2bf(acc[mt][nt][r] + bv);
        }
    }
}

// ======================= phase 2: sequential recurrence =====================
// 256 blocks: g = bid&3 (16 batch rows), jc = bid>>2 (16 h-cols).
// Wave w covers K-slice [256w, 256w+256) for all 4 gates.
//
// Protocol (1 block barrier per step, was 3):
//   * per-wave mailbox packets: producer wave w of block (g,jc) stores its
//     4 rows x 16 cols (128B contiguous) then its OWN u8 flag after its own
//     vmcnt(0) ack -- no barrier(C), no block-flag hop.
//   * consumer wave w polls the 64 wave-flags it needs (1 coalesced byte
//     load/lane + ballot), then coalesced-loads its 16-row x 256-col K-slice
//     (u64/lane, 512B per instruction) into its OWN LDS slice -- no
//     barrier(A). Early waves run poll->load->MFMA while late waves poll.
//   * flags are u8 with mod-256 wrap compare (flag in {t-1,t,t+1} only):
//     ready iff ((flag - t) & 255) <= 1. 1024 flags fit the 1KB region.
//   * part[] is double-buffered by t&1 so the single barrier(B) is race-free
//     under arbitrary wave skew. Mailbox ping-pong safety: any wave-flag(t)
//     happens-after barrier B(t) which happens-after all 4 waves' reads of
//     buf[(t-1)&1]; a producer writes buf[(t+1)&1] only after observing all
//     4 flags(t) of every block it covers -> no overwrite race.
__global__ __launch_bounds__(256, 1) void lstm_rec(const u16* __restrict__ whbf,
                                                   const u16* __restrict__ xproj,
                                                   u16* __restrict__ hbuf,
                                                   float* __restrict__ out,
                                                   u8* __restrict__ flgb) {
    __shared__ __align__(16) u16   h_sw[4][16][272];       // per-wave slice, pad->272 (4-way read grp)
    __shared__ float part[2][4][16][16][4];                 // [buf][gate][row][col][wave]
    __shared__ __align__(16) u16   how[4][4][16];           // [wave][rowInWave][col]

    const int tid  = threadIdx.x;
    const int w    = tid >> 6;
    const int lane = tid & 63;
    const int l15  = lane & 15, quad = lane >> 4;
    const int g    = blockIdx.x & 3;
    const int jc   = blockIdx.x >> 2;
    const int bbase = g * 16;
    const int crow = 4 * w + (lane >> 4);     // elementwise cell row (0..15)
    const int ccol = l15;                     // elementwise cell col (0..15)
    u8* fl   = flgb + g * 256;
    u8* myfl = fl + w * 64 + lane;            // flag idx = jc'*4+w'' = 64w+lane

    // Wh fragments: wave w holds K-slice [w*256, w*256+256) for all 4 gates.
    s16x8 bfrag[4][8];
#pragma unroll
    for (int gate = 0; gate < 4; ++gate) {
        const long nrow = (long)gate * 1024 + jc * 16 + l15;
#pragma unroll
        for (int kc = 0; kc < 8; ++kc)
            bfrag[gate][kc] = *(const s16x8*)&whbf[nrow * 1024 + w * 256 + kc * 32 + quad * 8];
    }

    float c_reg = 0.0f;
    // mailbox: u64 view; buffer stride 16384 u64 (128KB), group stride 4096,
    // jc stride 64, wave stride 16. Packet u16 layout [w][rr(4)][c(16)].
    u64* mb = (u64*)hbuf;
    u64* hb64[2] = { mb, mb + 16384 };

    // xp prefetch for t=0: per-lane, its cell, 4 gates
    const u16* xpcell = xproj + (long)(bbase + crow) * 512 * 4096 + jc * 16 + ccol;
    float xp[4];
#pragma unroll
    for (int gate = 0; gate < 4; ++gate)
        xp[gate] = bf2f(xpcell[(long)gate * 1024]);

    for (int t = 0; t < 512; ++t) {
        // ---- acquire h_{t-1} into this wave's LDS slice (no block barrier) ----
        if (t == 0) {
#pragma unroll
            for (int i = 0; i < 16; ++i)
                *(u64*)&h_sw[w][lane >> 2][i * 16 + (lane & 3) * 4] = 0ULL;
        } else {
            // poll 64 wave-flags (coalesced 64B line per wave)
            int pv = __hip_atomic_load(myfl, __ATOMIC_RELAXED, __HIP_MEMORY_SCOPE_AGENT);
            while (__ballot(((pv - t) & 255) > 1) != 0ULL) {
                __builtin_amdgcn_s_sleep(1);
                pv = __hip_atomic_load(myfl, __ATOMIC_RELAXED, __HIP_MEMORY_SCOPE_AGENT);
            }
            // coalesced slice load: iteration i = producer jc' = 16w+i,
            // lane covers u64 lane of the 512B packet block
            const u64* hs = hb64[(t + 1) & 1] + g * 4096 + w * 1024;
            u64 tmp[16];
#pragma unroll
            for (int i = 0; i < 16; ++i)
                tmp[i] = __hip_atomic_load(&hs[i * 64 + lane],
                                           __ATOMIC_RELAXED, __HIP_MEMORY_SCOPE_AGENT);
            // packet u16 idx within jc' block: w''*64+rr*16+c = lane*4 ->
            // row = w''*4+rr = lane>>2, slice col = i*16 + (lane&3)*4
#pragma unroll
            for (int i = 0; i < 16; ++i)
                *(u64*)&h_sw[w][lane >> 2][i * 16 + (lane & 3) * 4] = tmp[i];
        }

        // ---- MFMA: K-slice per wave, 4 gate accumulators (wave-local LDS) ----
        f32x4 acc[4];
#pragma unroll
        for (int gate = 0; gate < 4; ++gate) acc[gate] = 0.0f;
#pragma unroll
        for (int kc = 0; kc < 8; ++kc) {
            s16x8 a = *(const s16x8*)&h_sw[w][l15][kc * 32 + quad * 8];
            acc[0] = __builtin_amdgcn_mfma_f32_16x16x32_bf16(a, bfrag[0][kc], acc[0], 0, 0, 0);
            acc[1] = __builtin_amdgcn_mfma_f32_16x16x32_bf16(a, bfrag[1][kc], acc[1], 0, 0, 0);
            acc[2] = __builtin_amdgcn_mfma_f32_16x16x32_bf16(a, bfrag[2][kc], acc[2], 0, 0, 0);
            acc[3] = __builtin_amdgcn_mfma_f32_16x16x32_bf16(a, bfrag[3][kc], acc[3], 0, 0, 0);
        }
        // partial sums to LDS (double-buffered by t&1): D row = quad*4+r, col = l15
#pragma unroll
        for (int gate = 0; gate < 4; ++gate)
#pragma unroll
            for (int r = 0; r < 4; ++r)
                part[t & 1][gate][quad * 4 + r][l15][w] = acc[gate][r];
        __syncthreads();   // (B) the ONLY block barrier per step

        // ---- elementwise: each lane owns one (crow, ccol) cell ----
        float gv[4];
#pragma unroll
        for (int gate = 0; gate < 4; ++gate) {
            f32x4 p = *(const f32x4*)&part[t & 1][gate][crow][ccol][0];
            gv[gate] = ((p[0] + p[1]) + (p[2] + p[3])) + xp[gate];
        }
        float fv = fsigmoid(gv[0]);
        float iv = fsigmoid(gv[1]);
        float gg = ftanh   (gv[2]);
        float ov = fsigmoid(gv[3]);
        c_reg = fv * c_reg + iv * gg;
        float h = ov * ftanh(c_reg);

        if (t < 511) {
            // wave-local publish: packet store -> own ack -> own flag
            how[w][lane >> 4][ccol] = f2bf(h);
            if (lane < 16) {
                u64 hv = *(const u64*)&how[w][lane >> 2][(lane & 3) * 4];
                __hip_atomic_store(&hb64[t & 1][g * 4096 + jc * 64 + w * 16 + lane],
                                   hv, __ATOMIC_RELAXED, __HIP_MEMORY_SCOPE_AGENT);
            }
            __asm__ volatile("s_waitcnt vmcnt(0)" ::: "memory");  // this wave's stores acked
            if (lane == 0)
                __hip_atomic_store(&fl[jc * 4 + w], (u8)(t + 1),
                                   __ATOMIC_RELAXED, __HIP_MEMORY_SCOPE_AGENT);
        }

        long bg = bbase + crow;
        long j  = jc * 16 + ccol;
        out[(bg * 512 + t) * 1024 + j] = h;
        if (t == 511) {
            out[OUT_HFIN + bg * 1024 + j] = h;
            out[OUT_CFIN + bg * 1024 + j] = c_reg;
        } else {
            // xp prefetch for t+1 (after flag: off the critical path)
#pragma unroll
            for (int gate = 0; gate < 4; ++gate)
                xp[gate] = bf2f(xpcell[((long)t + 1) * 4096 + (long)gate * 1024]);
        }
    }
}

// ================================ launcher =================================
extern "C" void kernel_launch(void* const* d_in, const int* in_sizes, int n_in,
                              void* d_out, int out_size, void* d_ws, size_t ws_size,
                              hipStream_t stream) {
    const float* x    = (const float*)d_in[0];
    const float* W    = (const float*)d_in[1];
    const float* bias = (const float*)d_in[2];
    float* out = (float*)d_out;
    char*  ws  = (char*)d_ws;

    u16* xbf   = (u16*)(ws + OFF_XBF);
    u16* wx    = (u16*)(ws + OFF_WX);
    u16* wh    = (u16*)(ws + OFF_WH);
    u16* xproj = (u16*)(ws + OFF_XPROJ);
    u16* hbuf  = (u16*)(ws + OFF_HBUF);
    int* flg   = (int*)(ws + OFF_FLG);

    hipLaunchKernelGGL(prep_kernel, dim3(2048), dim3(256), 0, stream, x, W, xbf, wx, wh, flg);
    hipLaunchKernelGGL(xproj_gemm, dim3(32, 256), dim3(256), 0, stream, xbf, wx, bias, xproj);
    hipLaunchKernelGGL(lstm_rec, dim3(256), dim3(256), 0, stream, wh, xproj, hbuf, out, (u8*)flg);
}

// Round 3
// 2088.776 us; speedup vs baseline: 1.6050x; 1.6050x over previous
//
#include <hip/hip_runtime.h>
#include <hip/hip_bf16.h>
#include <stdint.h>

// Problem constants
#define B_SZ   64
#define L_SEQ  512
#define DIN    1024
#define HDIM   1024
// out layout: outputs [64*512*1024], h_fin [64*1024], c_fin [64*1024]
#define OUT_HFIN 33554432L
#define OUT_CFIN 33619968L

typedef float  f32x4 __attribute__((ext_vector_type(4)));
typedef short  s16x8 __attribute__((ext_vector_type(8)));
typedef unsigned short u16;
typedef unsigned int   u32;
typedef unsigned long long u64;

// ---- workspace layout (bytes) ----
// Mailbox REUSES the wx region (dead after xproj_gemm); zeroed by mbzero_kernel
// which runs between xproj_gemm and lstm_rec (stream-ordered).
#define OFF_XBF   0ULL
#define OFF_WX    67108864ULL
#define OFF_MB    67108864ULL      // 2 x 256KB tag-mailbox (ping-pong)
#define OFF_WH    75497472ULL
#define OFF_XPROJ 83886080ULL

static __device__ __forceinline__ u16 f2bf(float f) {
    __hip_bfloat16 h = __float2bfloat16(f);
    return *reinterpret_cast<u16*>(&h);
}
static __device__ __forceinline__ float bf2f(u16 u) {
    union { uint32_t i; float f; } v;
    v.i = ((uint32_t)u) << 16;
    return v.f;
}
static __device__ __forceinline__ float fsigmoid(float x) {
    return __builtin_amdgcn_rcpf(1.0f + __expf(-x));
}
static __device__ __forceinline__ float ftanh(float x) {
    return 1.0f - 2.0f * __builtin_amdgcn_rcpf(1.0f + __expf(2.0f * x));
}
// async global->LDS, 16B per lane. LDS ptr must be wave-uniform (HW writes
// base + lane*16); global ptr is per-lane.
static __device__ __forceinline__ void gload_lds16(const u16* g, u16* l) {
    __builtin_amdgcn_global_load_lds((const __attribute__((address_space(1))) void*)g,
                                     (__attribute__((address_space(3))) void*)l, 16, 0, 0);
}

// ============================ prep: fp32 -> bf16 ============================
__global__ void prep_kernel(const float* __restrict__ x, const float* __restrict__ W,
                            u16* __restrict__ xbf, u16* __restrict__ wx,
                            u16* __restrict__ wh) {
    long tid = (long)blockIdx.x * blockDim.x + threadIdx.x;
    long stride = (long)gridDim.x * blockDim.x;
    const long NX4 = 33554432 / 4;
    for (long i = tid; i < NX4; i += stride) {
        float4 v = ((const float4*)x)[i];
        ushort4 o;
        o.x = f2bf(v.x); o.y = f2bf(v.y); o.z = f2bf(v.z); o.w = f2bf(v.w);
        ((ushort4*)xbf)[i] = o;
    }
    const long NW4 = 8388608 / 4;
    for (long i = tid; i < NW4; i += stride) {
        float4 v = ((const float4*)W)[i];
        long f = i * 4;
        long n = f >> 11;        // row of W (2048 wide)
        long c = f & 2047;
        ushort4 o;
        o.x = f2bf(v.x); o.y = f2bf(v.y); o.z = f2bf(v.z); o.w = f2bf(v.w);
        u16* dst = (c < 1024) ? &wh[n * 1024 + c] : &wx[n * 1024 + (c - 1024)];
        *(ushort4*)dst = o;
    }
}

// ============ zero the tag-mailbox (runs AFTER xproj_gemm reads wx) =========
__global__ void mbzero_kernel(float4* __restrict__ mb) {
    int i = blockIdx.x * blockDim.x + threadIdx.x;   // 128*256 = 32768 * 16B = 512KB
    mb[i] = make_float4(0.f, 0.f, 0.f, 0.f);
}

// ==================== phase 1: x_proj = x @ Wx^T + b (bf16 out) =============
// m97-structure: global_load_lds dwordx4 staging + double-buffered LDS,
// one barrier per K-step.
__global__ __launch_bounds__(256) void xproj_gemm(const u16* __restrict__ xbf,
                                                  const u16* __restrict__ wxbf,
                                                  const float* __restrict__ bias,
                                                  u16* __restrict__ xproj) {
    __shared__ u16 As[2][128 * 32];
    __shared__ u16 Bs[2][128 * 32];
    const int tid  = threadIdx.x;
    const int lane = tid & 63;
    const int w    = tid >> 6;
    const int wm   = w >> 1, wn = w & 1;
    const int l15  = lane & 15, quad = lane >> 4;
    const int m0 = blockIdx.y * 128;
    const int n0 = blockIdx.x * 128;

    const u16* ga = xbf  + (long)(m0 + (tid >> 2)) * 1024 + (tid & 3) * 8;
    const u16* gb = wxbf + (long)(n0 + (tid >> 2)) * 1024 + (tid & 3) * 8;

    f32x4 acc[4][4];
#pragma unroll
    for (int i = 0; i < 4; ++i)
#pragma unroll
        for (int j = 0; j < 4; ++j) acc[i][j] = 0.0f;

#define STAGE(buf, k0)                                                    \
    do {                                                                  \
        gload_lds16(ga + (k0),         &As[buf][w * 512]);                \
        gload_lds16(ga + 65536 + (k0), &As[buf][2048 + w * 512]);         \
        gload_lds16(gb + (k0),         &Bs[buf][w * 512]);                \
        gload_lds16(gb + 65536 + (k0), &Bs[buf][2048 + w * 512]);         \
    } while (0)

    STAGE(0, 0);
    __syncthreads();

    for (int kt = 0; kt < 32; ++kt) {
        const int cur = kt & 1;
        if (kt < 31) STAGE(cur ^ 1, (kt + 1) * 32);

        s16x8 af[4], bfr[4];
#pragma unroll
        for (int mt = 0; mt < 4; ++mt)
            af[mt] = *(const s16x8*)&As[cur][(wm * 64 + mt * 16 + l15) * 32 + quad * 8];
#pragma unroll
        for (int nt = 0; nt < 4; ++nt)
            bfr[nt] = *(const s16x8*)&Bs[cur][(wn * 64 + nt * 16 + l15) * 32 + quad * 8];
#pragma unroll
        for (int mt = 0; mt < 4; ++mt)
#pragma unroll
            for (int nt = 0; nt < 4; ++nt)
                acc[mt][nt] = __builtin_amdgcn_mfma_f32_16x16x32_bf16(af[mt], bfr[nt], acc[mt][nt], 0, 0, 0);

        __syncthreads();
    }
#undef STAGE

#pragma unroll
    for (int nt = 0; nt < 4; ++nt) {
        int n = n0 + wn * 64 + nt * 16 + l15;
        float bv = bias[n];
#pragma unroll
        for (int mt = 0; mt < 4; ++mt) {
            int mbase = m0 + wm * 64 + mt * 16 + quad * 4;
#pragma unroll
            for (int r = 0; r < 4; ++r)
                xproj[(long)(mbase + r) * 4096 + n] = f2bf(acc[mt][nt][r] + bv);
        }
    }
}

// ======================= phase 2: sequential recurrence =====================
// 256 blocks: g = bid&3 (16 batch rows), jc = bid>>2 (16 h-cols).
// Wave w covers K-slice [256w, 256w+256) for all 4 gates.
//
// TAG-MAILBOX protocol (no flags, no vmcnt drain, 1 barrier/step):
//   slot = u64 { lo32: 2 x bf16 h-cols, hi32: tag }. 8B aligned accesses are
//   single-copy atomic, so ONE relaxed-atomic store publishes data+validity.
//   Producer (end of step t): shfl_xor pairs cols, even lanes store slots
//   with tag t+1. Consumer (step t): retry-load its 32 slots until all tags
//   == t. Flag-wait and data-load are the SAME LLC round trip.
//   Ping-pong by t&1. Safety (2-step skew impossible): producer B overwrites
//   parity-p slots (h_{t-1}'s buffer) only at step t+1, whose read phase
//   requires tag t+1 from every block A; A stores tag t+1 only after its
//   loads of h_{t-1} completed -> overwrite happens-after all reads.
//   part[] double-buffered by t&1 -> single barrier is race-free under skew
//   (any wave's partial-write(t+1) is ordered after barrier(B,t), which is
//   after every wave's elementwise-read of part[(t-1)&1]).
//   part layout [16 rows][4 waves][17 cols]: exact 2-way bank aliasing (free)
//   on both the MFMA-side writes and the elementwise reads (was 8-way).
__global__ __launch_bounds__(256, 1) void lstm_rec(const u16* __restrict__ whbf,
                                                   const u16* __restrict__ xproj,
                                                   u64* __restrict__ mbbuf,
                                                   float* __restrict__ out) {
    __shared__ __align__(16) u16 h_sw[4][16][272];   // per-wave K-slice, stride 272
    __shared__ float part[2][4][16][4][17];          // [buf][gate][row][wave][col+pad]

    const int tid  = threadIdx.x;
    const int w    = tid >> 6;
    const int lane = tid & 63;
    const int l15  = lane & 15, quad = lane >> 4;
    const int g    = blockIdx.x & 3;
    const int jc   = blockIdx.x >> 2;
    const int bbase = g * 16;
    const int crow = 4 * w + quad;            // elementwise cell row (0..15)
    const int ccol = l15;                     // elementwise cell col (0..15)

    // Wh fragments: wave w holds K-slice [w*256, w*256+256) for all 4 gates.
    // (128 VGPR-equiv; lives in AGPRs on gfx950's unified file.)
    s16x8 bfrag[4][8];
#pragma unroll
    for (int gate = 0; gate < 4; ++gate) {
        const long nrow = (long)gate * 1024 + jc * 16 + l15;
#pragma unroll
        for (int kc = 0; kc < 8; ++kc)
            bfrag[gate][kc] = *(const s16x8*)&whbf[nrow * 1024 + w * 256 + kc * 32 + quad * 8];
    }

    float c_reg = 0.0f;
    // mailbox: [buf 2][g 4][row 16][colpair 512] u64
    // consumer base for this wave: + row*512 + half*64 + lane
    const u64* mbrd0 = mbbuf + (u64)g * 8192 + w * 128 + lane;
    // producer slot for this lane (even l15 only): row = crow, cp = jc*8+l15/2
    u64* mbwr0 = mbbuf + (u64)g * 8192 + (u64)crow * 512 + jc * 8 + (l15 >> 1);

    // xp prefetch for t=0: per-lane, its cell, 4 gates
    const u16* xpcell = xproj + (long)(bbase + crow) * 512 * 4096 + jc * 16 + ccol;
    float xp[4];
#pragma unroll
    for (int gate = 0; gate < 4; ++gate)
        xp[gate] = bf2f(xpcell[(long)gate * 1024]);

    for (int t = 0; t < 512; ++t) {
        // ---- acquire h_{t-1}: tagged loads straight into this wave's slice ----
        if (t == 0) {
#pragma unroll
            for (int i = 0; i < 32; ++i)
                *(u32*)&h_sw[w][i >> 1][((i & 1) * 64 + lane) * 2] = 0u;
        } else {
            const u64* mbr = mbrd0 + ((t + 1) & 1) * 32768;
            u64 tmp[32];
            for (;;) {
#pragma unroll
                for (int i = 0; i < 32; ++i)
                    tmp[i] = __hip_atomic_load(&mbr[(i >> 1) * 512 + (i & 1) * 64],
                                               __ATOMIC_RELAXED, __HIP_MEMORY_SCOPE_AGENT);
                u32 bad = 0;
#pragma unroll
                for (int i = 0; i < 32; ++i)
                    bad |= ((u32)(tmp[i] >> 32)) ^ (u32)t;
                if (__ballot(bad != 0) == 0ULL) break;
            }
#pragma unroll
            for (int i = 0; i < 32; ++i)
                *(u32*)&h_sw[w][i >> 1][((i & 1) * 64 + lane) * 2] = (u32)tmp[i];
        }

        // ---- MFMA: K-slice per wave, 4 gate accumulators (wave-local LDS) ----
        f32x4 acc[4];
#pragma unroll
        for (int gate = 0; gate < 4; ++gate) acc[gate] = 0.0f;
#pragma unroll
        for (int kc = 0; kc < 8; ++kc) {
            s16x8 a = *(const s16x8*)&h_sw[w][l15][kc * 32 + quad * 8];
            acc[0] = __builtin_amdgcn_mfma_f32_16x16x32_bf16(a, bfrag[0][kc], acc[0], 0, 0, 0);
            acc[1] = __builtin_amdgcn_mfma_f32_16x16x32_bf16(a, bfrag[1][kc], acc[1], 0, 0, 0);
            acc[2] = __builtin_amdgcn_mfma_f32_16x16x32_bf16(a, bfrag[2][kc], acc[2], 0, 0, 0);
            acc[3] = __builtin_amdgcn_mfma_f32_16x16x32_bf16(a, bfrag[3][kc], acc[3], 0, 0, 0);
        }
        // partials: D row = quad*4+r, col = l15  (2-way-free layout)
#pragma unroll
        for (int gate = 0; gate < 4; ++gate)
#pragma unroll
            for (int r = 0; r < 4; ++r)
                part[t & 1][gate][quad * 4 + r][w][l15] = acc[gate][r];
        __syncthreads();   // the ONLY block barrier per step

        // ---- elementwise: each lane owns one (crow, ccol) cell ----
        float gv[4];
#pragma unroll
        for (int gate = 0; gate < 4; ++gate) {
            float p0 = part[t & 1][gate][crow][0][ccol];
            float p1 = part[t & 1][gate][crow][1][ccol];
            float p2 = part[t & 1][gate][crow][2][ccol];
            float p3 = part[t & 1][gate][crow][3][ccol];
            gv[gate] = ((p0 + p1) + (p2 + p3)) + xp[gate];
        }
        float fv = fsigmoid(gv[0]);
        float iv = fsigmoid(gv[1]);
        float gg = ftanh   (gv[2]);
        float ov = fsigmoid(gv[3]);
        c_reg = fv * c_reg + iv * gg;
        float h = ov * ftanh(c_reg);

        if (t < 511) {
            // publish: pair cols via shfl, ONE tagged u64 store per even lane.
            float hn = __shfl_xor(h, 1);
            if ((l15 & 1) == 0) {
                u32 data = (u32)f2bf(h) | ((u32)f2bf(hn) << 16);
                u64 slot = ((u64)(u32)(t + 1) << 32) | (u64)data;
                __hip_atomic_store(mbwr0 + (t & 1) * 32768, slot,
                                   __ATOMIC_RELAXED, __HIP_MEMORY_SCOPE_AGENT);
            }
        }

        long bg = bbase + crow;
        long j  = jc * 16 + ccol;
        out[(bg * 512 + t) * 1024 + j] = h;
        if (t == 511) {
            out[OUT_HFIN + bg * 1024 + j] = h;
            out[OUT_CFIN + bg * 1024 + j] = c_reg;
        } else {
            // xp prefetch for t+1 (off the critical path)
#pragma unroll
            for (int gate = 0; gate < 4; ++gate)
                xp[gate] = bf2f(xpcell[((long)t + 1) * 4096 + (long)gate * 1024]);
        }
    }
}

// ================================ launcher =================================
extern "C" void kernel_launch(void* const* d_in, const int* in_sizes, int n_in,
                              void* d_out, int out_size, void* d_ws, size_t ws_size,
                              hipStream_t stream) {
    const float* x    = (const float*)d_in[0];
    const float* W    = (const float*)d_in[1];
    const float* bias = (const float*)d_in[2];
    float* out = (float*)d_out;
    char*  ws  = (char*)d_ws;

    u16* xbf   = (u16*)(ws + OFF_XBF);
    u16* wx    = (u16*)(ws + OFF_WX);
    u16* wh    = (u16*)(ws + OFF_WH);
    u16* xproj = (u16*)(ws + OFF_XPROJ);
    u64* mb    = (u64*)(ws + OFF_MB);

    hipLaunchKernelGGL(prep_kernel, dim3(2048), dim3(256), 0, stream, x, W, xbf, wx, wh);
    hipLaunchKernelGGL(xproj_gemm, dim3(32, 256), dim3(256), 0, stream, xbf, wx, bias, xproj);
    hipLaunchKernelGGL(mbzero_kernel, dim3(128), dim3(256), 0, stream, (float4*)mb);
    hipLaunchKernelGGL(lstm_rec, dim3(256), dim3(256), 0, stream, wh, xproj, mb, out);
}